// Round 6
// baseline (520.168 us; speedup 1.0000x reference)
//
#include <hip/hip_runtime.h>
#include <hip/hip_bf16.h>
#include <math.h>

// Problem constants (from reference)
constexpr int N = 100000;    // nodes
constexpr int E = 3200000;   // edges
constexpr int FIN = 128, H1 = 64, H2 = 32, COUT = 2;

// Bucketing: 64 dst-nodes per bucket, fixed-capacity slices
constexpr int BUK_SHIFT = 6;
constexpr int BUK_NODES = 64;                          // 1 << BUK_SHIFT
constexpr int NBUK = (N + BUK_NODES - 1) / BUK_NODES;  // 1563
constexpr int CAP = 2560;             // slice capacity; mean fill 2048, sigma~45
// Keys are LD-MAJOR (key = ld*7 + seg): each node's list is contiguous
// (R0/R4's proven layout). R4 falsified address-throughput: 4x fewer gather
// addresses, identical 89.3us & FETCH 288MB -> the aggregate saturates the
// L2-miss path at ~3.6 TB/s. R5 lever: FEATURE SLICING — aggregate in
// 16-feature passes so the gather working set (N*16*2B = 3.2MB) fits the 4MB
// per-XCD L2. Edge lists untouched (R1-R3: src-phasing fragments lists ->
// latency-bound). y stored slice-major [pass][N][16] so slices are contiguous
// (no line-granularity waste). csr nt-loads + nt-stores of out protect slice
// residency.
constexpr int SEG_SHIFT = 14;
constexpr int NSEG = 7;
constexpr int KEYS = BUK_NODES * NSEG;                 // 448 (ld-major!)
constexpr int RP_STR = BUK_NODES + 1;                  // 65 rowptr slots per bucket

constexpr int MS_TPB = 1024;
constexpr int MS_EPT = 24;                             // edges per thread
constexpr int CHUNK = MS_TPB * MS_EPT;                 // 24576
constexpr int MS_WGS = (E + CHUNK - 1) / CHUNK;        // 131

typedef float f32x4 __attribute__((ext_vector_type(4)));   // native clang vec for nt-store

// ---------------- init: gcursor[b] = b*CAP ----------------
__global__ void k_initcur(int* __restrict__ gcursor) {
    int i = blockIdx.x * blockDim.x + threadIdx.x;
    if (i < NBUK) gcursor[i] = i * CAP;
}

// ---------------- multisplit into fixed-capacity bucket slices ----------------
// packed entry: src (17 bits) | local_node (6 bits) << 17
__global__ __launch_bounds__(MS_TPB)
void k_mslice(const int* __restrict__ src, const int* __restrict__ dst,
              int* __restrict__ gcursor, unsigned* __restrict__ ebuf) {
    __shared__ int cnt[NBUK];
    __shared__ int base[NBUK];
    const int t = threadIdx.x;
    for (int i = t; i < NBUK; i += MS_TPB) cnt[i] = 0;
    __syncthreads();
    const int e0 = blockIdx.x * CHUNK;

    int rb[MS_EPT];
    unsigned rv[MS_EPT];
#pragma unroll
    for (int j = 0; j < MS_EPT; ++j) {
        int e = e0 + j * MS_TPB + t;
        if (e < E) {
            int d = dst[e];
            int b = d >> BUK_SHIFT;
            rb[j] = b;
            rv[j] = (unsigned)src[e] | ((unsigned)(d & (BUK_NODES - 1)) << 17);
            atomicAdd(&cnt[b], 1);
        } else {
            rb[j] = -1; rv[j] = 0;
        }
    }
    __syncthreads();
    for (int i = t; i < NBUK; i += MS_TPB) {
        int c = cnt[i];
        base[i] = c ? atomicAdd(&gcursor[i], c) : 0;
    }
    __syncthreads();
    for (int i = t; i < NBUK; i += MS_TPB) cnt[i] = 0;
    __syncthreads();
#pragma unroll
    for (int j = 0; j < MS_EPT; ++j) {
        int b = rb[j];
        if (b >= 0) {
            int r = atomicAdd(&cnt[b], 1);
            int p = base[b] + r;
            if (p < (b + 1) * CAP) ebuf[p] = rv[j];   // overflow guard (statistically impossible)
        }
    }
}

// ---------------- per-bucket build: counting-sort by (local_dst, seg) ----------------
// ld-major key => each node's list is contiguous AND seg-sorted within.
// Emits rp[b*65 + ld] = node list start, rp[b*65+64] = slice end; dinv.
__global__ __launch_bounds__(256)
void k_build(const int* __restrict__ gcursor, unsigned* __restrict__ ebuf,
             int* __restrict__ rp, float* __restrict__ dinv) {
    __shared__ unsigned ent[CAP];
    __shared__ int cnt[512];
    __shared__ int sa[512];
    __shared__ int sb[512];
    __shared__ int cur[512];
    const int b = blockIdx.x;
    const int t = threadIdx.x;
    int fill = gcursor[b] - b * CAP;
    if (fill > CAP) fill = CAP;
    const int gbase = b * CAP;

    cnt[t] = 0; cnt[t + 256] = 0;
    __syncthreads();
    for (int j = t; j < fill; j += 256) {
        unsigned v = ebuf[gbase + j];
        ent[j] = v;
        int key = (int)(v >> 17) * NSEG + (int)((v & 0x1FFFFu) >> SEG_SHIFT);
        atomicAdd(&cnt[key], 1);
    }
    __syncthreads();
    sa[t] = cnt[t]; sa[t + 256] = cnt[t + 256];
    __syncthreads();
    int* pin = sa; int* pout = sb;
    for (int off = 1; off < 512; off <<= 1) {
        pout[t]       = pin[t]       + ((t >= off)       ? pin[t - off]       : 0);
        pout[t + 256] = pin[t + 256] + ((t + 256 >= off) ? pin[t + 256 - off] : 0);
        __syncthreads();
        int* tmp = pin; pin = pout; pout = tmp;
    }
    {
        int ex0 = pin[t] - cnt[t];
        int ex1 = pin[t + 256] - cnt[t + 256];
        cur[t] = gbase + ex0;
        cur[t + 256] = gbase + ex1;
        // node list start = start of its first (seg=0) key
        if (t < KEYS && (t % NSEG) == 0)
            rp[b * RP_STR + t / NSEG] = gbase + ex0;
        int k2 = t + 256;
        if (k2 < KEYS && (k2 % NSEG) == 0)
            rp[b * RP_STR + k2 / NSEG] = gbase + ex1;
        if (t == 0) rp[b * RP_STR + BUK_NODES] = gbase + fill;   // sentinel
    }
    if (t < BUK_NODES) {
        int deg = 0;
#pragma unroll
        for (int s = 0; s < NSEG; ++s) deg += cnt[t * NSEG + s];
        int node = (b << BUK_SHIFT) + t;
        if (node < N) dinv[node] = rsqrtf((float)deg + 1.0f);  // self-loop included
    }
    __syncthreads();
    for (int j = t; j < fill; j += 256) {
        unsigned v = ent[j];
        int key = (int)(v >> 17) * NSEG + (int)((v & 0x1FFFFu) >> SEG_SHIFT);
        int p = atomicAdd(&cur[key], 1);
        ebuf[p] = v & 0x1FFFFu;   // sorted, plain src
    }
}

// ---------------- register-tiled GEMM + dinv scale, bf16 SLICE-MAJOR output ----
// Output layout: y[pass][N][16] bf16 (pass = 16-feature slice). Each slice is
// a contiguous 3.2MB region -> L2-resident during the matching aggregate pass.
template<int FI, int FO>
__global__ __launch_bounds__(256)
void k_gemm_tile_bf(const float* __restrict__ h, const float* __restrict__ Wg,
                    const float* __restrict__ dinv, __hip_bfloat16* __restrict__ y) {
    static_assert(FO % 16 == 0, "slice width 16");
    constexpr int TX  = FO / 4;
    constexpr int TY  = 256 / TX;
    constexpr int RPT = 64 / TY;
    constexpr int XS  = 68;
    constexpr int KQ  = FI / 4;

    __shared__ float xsT[FI][XS];

    const int tid = threadIdx.x;
    const int tx = tid % TX;
    const int ty = tid / TX;
    const int row0 = blockIdx.x * 64;

    for (int idx = tid; idx < 64 * KQ; idx += 256) {
        int g   = idx / 8;
        int rlo = idx % 8;
        int k4  = g % KQ;
        int rhi = g / KQ;
        int r   = rlo + 8 * rhi;
        int row = row0 + r;
        float4 v = make_float4(0.f, 0.f, 0.f, 0.f);
        if (row < N) v = *(const float4*)(h + (size_t)row * FI + 4 * k4);
        xsT[4 * k4 + 0][r] = v.x;
        xsT[4 * k4 + 1][r] = v.y;
        xsT[4 * k4 + 2][r] = v.z;
        xsT[4 * k4 + 3][r] = v.w;
    }
    __syncthreads();

    float acc[RPT][4];
#pragma unroll
    for (int i = 0; i < RPT; ++i)
#pragma unroll
        for (int c = 0; c < 4; ++c) acc[i][c] = 0.0f;

#pragma unroll 4
    for (int k = 0; k < FI; ++k) {
        const float4 wv = *(const float4*)(Wg + (size_t)k * FO + 4 * tx);
        float xv[RPT];
        if constexpr (RPT == 4) {
            float4 t = *(const float4*)&xsT[k][4 * ty];
            xv[0] = t.x; xv[1] = t.y; xv[2] = t.z; xv[3] = t.w;
        } else {
            float2 t = *(const float2*)&xsT[k][2 * ty];
            xv[0] = t.x; xv[1] = t.y;
        }
#pragma unroll
        for (int i = 0; i < RPT; ++i) {
            acc[i][0] = fmaf(xv[i], wv.x, acc[i][0]);
            acc[i][1] = fmaf(xv[i], wv.y, acc[i][1]);
            acc[i][2] = fmaf(xv[i], wv.z, acc[i][2]);
            acc[i][3] = fmaf(xv[i], wv.w, acc[i][3]);
        }
    }

    const int p  = (4 * tx) / 16;      // slice index
    const int fo = (4 * tx) % 16;      // offset within slice row
#pragma unroll
    for (int i = 0; i < RPT; ++i) {
        int row = row0 + ty * RPT + i;
        if (row >= N) continue;
        float di = dinv[row];
        auto cvt = [](float f) -> unsigned short {
            __hip_bfloat16 b = __float2bfloat16(f);
            return *reinterpret_cast<unsigned short*>(&b);
        };
        ushort4 pk;
        pk.x = cvt(di * acc[i][0]);
        pk.y = cvt(di * acc[i][1]);
        pk.z = cvt(di * acc[i][2]);
        pk.w = cvt(di * acc[i][3]);
        *(ushort4*)&y[((size_t)p * N + row) * 16 + fo] = pk;
    }
}

// ---------------- fused GEMM + dinv scale, fp32 output (layer 3, tiny) ----------------
template<int FI, int FO, int ROWS>
__global__ __launch_bounds__(FO * ROWS)
void k_gemm_scale(const float* __restrict__ h, const float* __restrict__ W,
                  const float* __restrict__ dinv, float* __restrict__ y) {
    __shared__ float xs[ROWS][FI];
    const int j = threadIdx.x;
    const int r = threadIdx.y;
    const int row0 = blockIdx.x * ROWS;
    const int tid = r * FO + j;
    constexpr int NT = FO * ROWS;
    for (int t = tid; t < ROWS * FI; t += NT) {
        int rr = t / FI, kk = t % FI;
        int row = row0 + rr;
        xs[rr][kk] = (row < N) ? h[(size_t)row * FI + kk] : 0.0f;
    }
    __syncthreads();
    const int row = row0 + r;
    if (row >= N) return;
    float acc = 0.0f;
#pragma unroll
    for (int k = 0; k < FI; ++k)
        acc = fmaf(xs[r][k], W[k * FO + j], acc);
    y[(size_t)row * FO + j] = dinv[row] * acc;
}

// ---------------- feature-sliced CSR aggregate (bf16 gather) ------------------
// y layout: [NPASS][N][16] bf16. Internal pass loop (unroll 1): all blocks
// co-resident (no LDS, ~60 VGPR -> grid 782 << capacity) sweep slices in the
// same order; per-pass gather working set = 3.2MB, L2-resident per XCD.
// Inner loop = R4's proven branch-free named unroll-8 batch (the only form
// the scheduler keeps 8 gathers in flight). csr nt-loads + nt-stores of out
// keep the slice from being evicted.
template<int F, bool RELU>
__global__ __launch_bounds__(256)
void k_agg_pw(const int* __restrict__ rp, const unsigned* __restrict__ csr,
              const __hip_bfloat16* __restrict__ y, const float* __restrict__ dinv,
              const float* __restrict__ b, float* __restrict__ out) {
    constexpr int NPASS = F / 16;      // 16-feature slices
    constexpr int QPP   = 2;           // uint4 per slice row (16 bf16 = 2 x 16B)
    constexpr int NPB   = 256 / QPP;   // 128 nodes per block
    const int fp = threadIdx.x;        // 0..1: which uint4 of the slice row
    const int n = blockIdx.x * NPB + threadIdx.y;
    if (n >= N) return;
    const uint4* yq = (const uint4*)y;

    const int rb = (n >> BUK_SHIFT) * RP_STR + (n & (BUK_NODES - 1));
    const int j0 = rp[rb];
    const int j1 = rp[rb + 1];
    const float di = dinv[n];

    auto unpk = [](unsigned w, float& lo, float& hi) {
        lo = __uint_as_float(w << 16);
        hi = __uint_as_float(w & 0xffff0000u);
    };

#pragma unroll 1
    for (int p = 0; p < NPASS; ++p) {
        const size_t sbase = (size_t)p * N * QPP + fp;   // slice base (uint4 units)
        float acc[8];
        {   // self-loop init
            uint4 v = yq[sbase + (size_t)n * QPP];
            unpk(v.x, acc[0], acc[1]); unpk(v.y, acc[2], acc[3]);
            unpk(v.z, acc[4], acc[5]); unpk(v.w, acc[6], acc[7]);
        }
        auto accum = [&](uint4 v) {
            float l0, h0, l1, h1, l2, h2, l3, h3;
            unpk(v.x, l0, h0); unpk(v.y, l1, h1);
            unpk(v.z, l2, h2); unpk(v.w, l3, h3);
            acc[0] += l0; acc[1] += h0; acc[2] += l1; acc[3] += h1;
            acc[4] += l2; acc[5] += h2; acc[6] += l3; acc[7] += h3;
        };

        int j = j0;
        for (; j + 8 <= j1; j += 8) {   // 8 x 16B gathers in flight per lane
            int s0 = (int)__builtin_nontemporal_load(&csr[j]);
            int s1 = (int)__builtin_nontemporal_load(&csr[j + 1]);
            int s2 = (int)__builtin_nontemporal_load(&csr[j + 2]);
            int s3 = (int)__builtin_nontemporal_load(&csr[j + 3]);
            int s4 = (int)__builtin_nontemporal_load(&csr[j + 4]);
            int s5 = (int)__builtin_nontemporal_load(&csr[j + 5]);
            int s6 = (int)__builtin_nontemporal_load(&csr[j + 6]);
            int s7 = (int)__builtin_nontemporal_load(&csr[j + 7]);
            uint4 v0 = yq[sbase + (size_t)s0 * QPP], v1 = yq[sbase + (size_t)s1 * QPP];
            uint4 v2 = yq[sbase + (size_t)s2 * QPP], v3 = yq[sbase + (size_t)s3 * QPP];
            uint4 v4 = yq[sbase + (size_t)s4 * QPP], v5 = yq[sbase + (size_t)s5 * QPP];
            uint4 v6 = yq[sbase + (size_t)s6 * QPP], v7 = yq[sbase + (size_t)s7 * QPP];
            accum(v0); accum(v1); accum(v2); accum(v3);
            accum(v4); accum(v5); accum(v6); accum(v7);
        }
        for (; j < j1; ++j) {
            int s = (int)__builtin_nontemporal_load(&csr[j]);
            accum(yq[sbase + (size_t)s * QPP]);
        }

        // epilogue for this slice: scale, bias, relu, nt-store
        const float* bp = b + p * 16 + 8 * fp;
        f32x4 o0, o1;
        o0.x = fmaf(di, acc[0], bp[0]);
        o0.y = fmaf(di, acc[1], bp[1]);
        o0.z = fmaf(di, acc[2], bp[2]);
        o0.w = fmaf(di, acc[3], bp[3]);
        o1.x = fmaf(di, acc[4], bp[4]);
        o1.y = fmaf(di, acc[5], bp[5]);
        o1.z = fmaf(di, acc[6], bp[6]);
        o1.w = fmaf(di, acc[7], bp[7]);
        if (RELU) {
            o0.x = fmaxf(o0.x, 0.f); o0.y = fmaxf(o0.y, 0.f);
            o0.z = fmaxf(o0.z, 0.f); o0.w = fmaxf(o0.w, 0.f);
            o1.x = fmaxf(o1.x, 0.f); o1.y = fmaxf(o1.y, 0.f);
            o1.z = fmaxf(o1.z, 0.f); o1.w = fmaxf(o1.w, 0.f);
        }
        float* op = out + (size_t)n * F + p * 16 + 8 * fp;
        __builtin_nontemporal_store(o0, (f32x4*)op);
        __builtin_nontemporal_store(o1, (f32x4*)(op + 4));
    }
}

// ---------------- layer 3 aggregate + log_softmax (2 classes) ----------------
__global__ __launch_bounds__(256)
void k_final(const int* __restrict__ rp, const unsigned* __restrict__ csr,
             const float* __restrict__ y, const float* __restrict__ dinv,
             const float* __restrict__ bias, float* __restrict__ out) {
    const int c = threadIdx.x;                       // class 0/1
    const int n = blockIdx.x * 128 + threadIdx.y;    // node
    float z = 0.0f;
    if (n < N) {
        const int rb = (n >> BUK_SHIFT) * RP_STR + (n & (BUK_NODES - 1));
        int j = rp[rb];
        const int j1 = rp[rb + 1];
        float acc = y[2 * n + c];
        for (; j + 4 <= j1; j += 4) {
            int s0 = (int)csr[j], s1 = (int)csr[j + 1], s2 = (int)csr[j + 2], s3 = (int)csr[j + 3];
            float a0 = y[2 * s0 + c], a1 = y[2 * s1 + c];
            float a2 = y[2 * s2 + c], a3 = y[2 * s3 + c];
            acc += (a0 + a1) + (a2 + a3);
        }
        for (; j < j1; ++j) acc += y[2 * (int)csr[j] + c];
        z = fmaf(dinv[n], acc, bias[c]);
    }
    float zo = __shfl_xor(z, 1);
    if (n < N) {
        float m = fmaxf(z, zo);
        float lse = m + logf(expf(z - m) + expf(zo - m));
        out[2 * n + c] = z - lse;
    }
}

extern "C" void kernel_launch(void* const* d_in, const int* in_sizes, int n_in,
                              void* d_out, int out_size, void* d_ws, size_t ws_size,
                              hipStream_t stream) {
    const float* x   = (const float*)d_in[0];
    const int*   ei  = (const int*)d_in[1];
    const float* W1  = (const float*)d_in[2];
    const float* b1  = (const float*)d_in[3];
    const float* W2  = (const float*)d_in[4];
    const float* b2  = (const float*)d_in[5];
    const float* W3  = (const float*)d_in[6];
    const float* b3  = (const float*)d_in[7];
    float* out = (float*)d_out;

    const int* src = ei;
    const int* dst = ei + E;

    // workspace layout
    char* p = (char*)d_ws;
    float*    dinv    = (float*)p;    p += (size_t)N * 4;
    int*      gcursor = (int*)p;      p += (size_t)NBUK * 4;
    int*      rp      = (int*)p;      p += (size_t)NBUK * RP_STR * 4;  // 406 KB
    unsigned* ebuf    = (unsigned*)p; p += (size_t)NBUK * CAP * 4;     // 16 MB
    char*     bufA    = p;            p += (size_t)N * 64 * 4;         // 25.6 MB
    char*     bufB    = p;            p += (size_t)N * 64 * 4;         // 25.6 MB

    __hip_bfloat16* y1 = (__hip_bfloat16*)bufA;     // [4][N][16] bf16
    float*          h1 = (float*)bufB;              // N*64*4 B
    __hip_bfloat16* y2 = (__hip_bfloat16*)bufA;     // [2][N][16] bf16 (y1 dead)
    float*          h2 = (float*)(bufA + (size_t)N * H2 * 2);  // N*32*4 B
    float*          y3 = (float*)bufB;              // N*2*4 B (h1 dead)

    // ---- edge structure build ----
    k_initcur<<<(NBUK + 255) / 256, 256, 0, stream>>>(gcursor);
    k_mslice <<<MS_WGS, MS_TPB, 0, stream>>>(src, dst, gcursor, ebuf);
    k_build  <<<NBUK, 256, 0, stream>>>(gcursor, ebuf, rp, dinv);

    // ---- layer 1: 128 -> 64 ----
    k_gemm_tile_bf<FIN, H1><<<(N + 63) / 64, 256, 0, stream>>>(x, W1, dinv, y1);
    k_agg_pw<H1, true><<<(N + 127) / 128, dim3(2, 128), 0, stream>>>(rp, ebuf, y1, dinv, b1, h1);

    // ---- layer 2: 64 -> 32 ----
    k_gemm_tile_bf<H1, H2><<<(N + 63) / 64, 256, 0, stream>>>(h1, W2, dinv, y2);
    k_agg_pw<H2, true><<<(N + 127) / 128, dim3(2, 128), 0, stream>>>(rp, ebuf, y2, dinv, b2, h2);

    // ---- layer 3: 32 -> 2 + log_softmax ----
    k_gemm_scale<H2, COUT, 128><<<(N + 127) / 128, dim3(COUT, 128), 0, stream>>>(h2, W3, dinv, y3);
    k_final<<<(N + 127) / 128, dim3(2, 128), 0, stream>>>(rp, ebuf, y3, dinv, b3, out);
}

// Round 7
// 470.957 us; speedup vs baseline: 1.1045x; 1.1045x over previous
//
#include <hip/hip_runtime.h>
#include <hip/hip_bf16.h>
#include <math.h>

// Problem constants (from reference)
constexpr int N = 100000;    // nodes
constexpr int E = 3200000;   // edges
constexpr int FIN = 128, H1 = 64, H2 = 32, COUT = 2;

// Bucketing: 64 dst-nodes per bucket, fixed-capacity slices
constexpr int BUK_SHIFT = 6;
constexpr int BUK_NODES = 64;                          // 1 << BUK_SHIFT
constexpr int NBUK = (N + BUK_NODES - 1) / BUK_NODES;  // 1563
constexpr int CAP = 2560;             // slice capacity; mean fill 2048, sigma~45
// Keys LD-MAJOR (key = ld*7 + seg): node lists contiguous (R0/R4 proven).
// R4: aggregate saturates L2-miss path at ~3.6 TB/s (byte-bound).
// R5/R6: feature slicing (16-feat slices, 3.2MB < 4MB L2) cut FETCH but the
// in-kernel pass loop drifted (thread-level) -> 2-3 slices live -> thrash,
// AND 2 lanes/node collapsed parallelism (25% occ, 1.56 TB/s).
// R7: one LAUNCH per pass (architectural phase alignment) + 8 threads/node
// (2 feature-halves x 4 list-quarters -> 3125 blocks/pass, R4-scale MLP);
// tail handled as a single masked batch (straight-line, loads stay batched).
constexpr int SEG_SHIFT = 14;
constexpr int NSEG = 7;
constexpr int KEYS = BUK_NODES * NSEG;                 // 448 (ld-major!)
constexpr int RP_STR = BUK_NODES + 1;                  // 65 rowptr slots per bucket

constexpr int MS_TPB = 1024;
constexpr int MS_EPT = 24;                             // edges per thread
constexpr int CHUNK = MS_TPB * MS_EPT;                 // 24576
constexpr int MS_WGS = (E + CHUNK - 1) / CHUNK;        // 131

typedef float f32x4 __attribute__((ext_vector_type(4)));   // native clang vec for nt-store

// ---------------- init: gcursor[b] = b*CAP ----------------
__global__ void k_initcur(int* __restrict__ gcursor) {
    int i = blockIdx.x * blockDim.x + threadIdx.x;
    if (i < NBUK) gcursor[i] = i * CAP;
}

// ---------------- multisplit into fixed-capacity bucket slices ----------------
// packed entry: src (17 bits) | local_node (6 bits) << 17
__global__ __launch_bounds__(MS_TPB)
void k_mslice(const int* __restrict__ src, const int* __restrict__ dst,
              int* __restrict__ gcursor, unsigned* __restrict__ ebuf) {
    __shared__ int cnt[NBUK];
    __shared__ int base[NBUK];
    const int t = threadIdx.x;
    for (int i = t; i < NBUK; i += MS_TPB) cnt[i] = 0;
    __syncthreads();
    const int e0 = blockIdx.x * CHUNK;

    int rb[MS_EPT];
    unsigned rv[MS_EPT];
#pragma unroll
    for (int j = 0; j < MS_EPT; ++j) {
        int e = e0 + j * MS_TPB + t;
        if (e < E) {
            int d = dst[e];
            int b = d >> BUK_SHIFT;
            rb[j] = b;
            rv[j] = (unsigned)src[e] | ((unsigned)(d & (BUK_NODES - 1)) << 17);
            atomicAdd(&cnt[b], 1);
        } else {
            rb[j] = -1; rv[j] = 0;
        }
    }
    __syncthreads();
    for (int i = t; i < NBUK; i += MS_TPB) {
        int c = cnt[i];
        base[i] = c ? atomicAdd(&gcursor[i], c) : 0;
    }
    __syncthreads();
    for (int i = t; i < NBUK; i += MS_TPB) cnt[i] = 0;
    __syncthreads();
#pragma unroll
    for (int j = 0; j < MS_EPT; ++j) {
        int b = rb[j];
        if (b >= 0) {
            int r = atomicAdd(&cnt[b], 1);
            int p = base[b] + r;
            if (p < (b + 1) * CAP) ebuf[p] = rv[j];   // overflow guard (statistically impossible)
        }
    }
}

// ---------------- per-bucket build: counting-sort by (local_dst, seg) ----------------
// ld-major key => each node's list is contiguous AND seg-sorted within.
// Emits rp[b*65 + ld] = node list start, rp[b*65+64] = slice end; dinv.
__global__ __launch_bounds__(256)
void k_build(const int* __restrict__ gcursor, unsigned* __restrict__ ebuf,
             int* __restrict__ rp, float* __restrict__ dinv) {
    __shared__ unsigned ent[CAP];
    __shared__ int cnt[512];
    __shared__ int sa[512];
    __shared__ int sb[512];
    __shared__ int cur[512];
    const int b = blockIdx.x;
    const int t = threadIdx.x;
    int fill = gcursor[b] - b * CAP;
    if (fill > CAP) fill = CAP;
    const int gbase = b * CAP;

    cnt[t] = 0; cnt[t + 256] = 0;
    __syncthreads();
    for (int j = t; j < fill; j += 256) {
        unsigned v = ebuf[gbase + j];
        ent[j] = v;
        int key = (int)(v >> 17) * NSEG + (int)((v & 0x1FFFFu) >> SEG_SHIFT);
        atomicAdd(&cnt[key], 1);
    }
    __syncthreads();
    sa[t] = cnt[t]; sa[t + 256] = cnt[t + 256];
    __syncthreads();
    int* pin = sa; int* pout = sb;
    for (int off = 1; off < 512; off <<= 1) {
        pout[t]       = pin[t]       + ((t >= off)       ? pin[t - off]       : 0);
        pout[t + 256] = pin[t + 256] + ((t + 256 >= off) ? pin[t + 256 - off] : 0);
        __syncthreads();
        int* tmp = pin; pin = pout; pout = tmp;
    }
    {
        int ex0 = pin[t] - cnt[t];
        int ex1 = pin[t + 256] - cnt[t + 256];
        cur[t] = gbase + ex0;
        cur[t + 256] = gbase + ex1;
        // node list start = start of its first (seg=0) key
        if (t < KEYS && (t % NSEG) == 0)
            rp[b * RP_STR + t / NSEG] = gbase + ex0;
        int k2 = t + 256;
        if (k2 < KEYS && (k2 % NSEG) == 0)
            rp[b * RP_STR + k2 / NSEG] = gbase + ex1;
        if (t == 0) rp[b * RP_STR + BUK_NODES] = gbase + fill;   // sentinel
    }
    if (t < BUK_NODES) {
        int deg = 0;
#pragma unroll
        for (int s = 0; s < NSEG; ++s) deg += cnt[t * NSEG + s];
        int node = (b << BUK_SHIFT) + t;
        if (node < N) dinv[node] = rsqrtf((float)deg + 1.0f);  // self-loop included
    }
    __syncthreads();
    for (int j = t; j < fill; j += 256) {
        unsigned v = ent[j];
        int key = (int)(v >> 17) * NSEG + (int)((v & 0x1FFFFu) >> SEG_SHIFT);
        int p = atomicAdd(&cur[key], 1);
        ebuf[p] = v & 0x1FFFFu;   // sorted, plain src
    }
}

// ---------------- register-tiled GEMM + dinv scale, bf16 SLICE-MAJOR output ----
// Output layout: y[pass][N][16] bf16 (pass = 16-feature slice). Each slice is
// a contiguous 3.2MB region -> L2-resident during the matching aggregate pass.
template<int FI, int FO>
__global__ __launch_bounds__(256)
void k_gemm_tile_bf(const float* __restrict__ h, const float* __restrict__ Wg,
                    const float* __restrict__ dinv, __hip_bfloat16* __restrict__ y) {
    static_assert(FO % 16 == 0, "slice width 16");
    constexpr int TX  = FO / 4;
    constexpr int TY  = 256 / TX;
    constexpr int RPT = 64 / TY;
    constexpr int XS  = 68;
    constexpr int KQ  = FI / 4;

    __shared__ float xsT[FI][XS];

    const int tid = threadIdx.x;
    const int tx = tid % TX;
    const int ty = tid / TX;
    const int row0 = blockIdx.x * 64;

    for (int idx = tid; idx < 64 * KQ; idx += 256) {
        int g   = idx / 8;
        int rlo = idx % 8;
        int k4  = g % KQ;
        int rhi = g / KQ;
        int r   = rlo + 8 * rhi;
        int row = row0 + r;
        float4 v = make_float4(0.f, 0.f, 0.f, 0.f);
        if (row < N) v = *(const float4*)(h + (size_t)row * FI + 4 * k4);
        xsT[4 * k4 + 0][r] = v.x;
        xsT[4 * k4 + 1][r] = v.y;
        xsT[4 * k4 + 2][r] = v.z;
        xsT[4 * k4 + 3][r] = v.w;
    }
    __syncthreads();

    float acc[RPT][4];
#pragma unroll
    for (int i = 0; i < RPT; ++i)
#pragma unroll
        for (int c = 0; c < 4; ++c) acc[i][c] = 0.0f;

#pragma unroll 4
    for (int k = 0; k < FI; ++k) {
        const float4 wv = *(const float4*)(Wg + (size_t)k * FO + 4 * tx);
        float xv[RPT];
        if constexpr (RPT == 4) {
            float4 t = *(const float4*)&xsT[k][4 * ty];
            xv[0] = t.x; xv[1] = t.y; xv[2] = t.z; xv[3] = t.w;
        } else {
            float2 t = *(const float2*)&xsT[k][2 * ty];
            xv[0] = t.x; xv[1] = t.y;
        }
#pragma unroll
        for (int i = 0; i < RPT; ++i) {
            acc[i][0] = fmaf(xv[i], wv.x, acc[i][0]);
            acc[i][1] = fmaf(xv[i], wv.y, acc[i][1]);
            acc[i][2] = fmaf(xv[i], wv.z, acc[i][2]);
            acc[i][3] = fmaf(xv[i], wv.w, acc[i][3]);
        }
    }

    const int p  = (4 * tx) / 16;      // slice index
    const int fo = (4 * tx) % 16;      // offset within slice row
#pragma unroll
    for (int i = 0; i < RPT; ++i) {
        int row = row0 + ty * RPT + i;
        if (row >= N) continue;
        float di = dinv[row];
        auto cvt = [](float f) -> unsigned short {
            __hip_bfloat16 b = __float2bfloat16(f);
            return *reinterpret_cast<unsigned short*>(&b);
        };
        ushort4 pk;
        pk.x = cvt(di * acc[i][0]);
        pk.y = cvt(di * acc[i][1]);
        pk.z = cvt(di * acc[i][2]);
        pk.w = cvt(di * acc[i][3]);
        *(ushort4*)&y[((size_t)p * N + row) * 16 + fo] = pk;
    }
}

// ---------------- fused GEMM + dinv scale, fp32 output (layer 3, tiny) ----------------
template<int FI, int FO, int ROWS>
__global__ __launch_bounds__(FO * ROWS)
void k_gemm_scale(const float* __restrict__ h, const float* __restrict__ W,
                  const float* __restrict__ dinv, float* __restrict__ y) {
    __shared__ float xs[ROWS][FI];
    const int j = threadIdx.x;
    const int r = threadIdx.y;
    const int row0 = blockIdx.x * ROWS;
    const int tid = r * FO + j;
    constexpr int NT = FO * ROWS;
    for (int t = tid; t < ROWS * FI; t += NT) {
        int rr = t / FI, kk = t % FI;
        int row = row0 + rr;
        xs[rr][kk] = (row < N) ? h[(size_t)row * FI + kk] : 0.0f;
    }
    __syncthreads();
    const int row = row0 + r;
    if (row >= N) return;
    float acc = 0.0f;
#pragma unroll
    for (int k = 0; k < FI; ++k)
        acc = fmaf(xs[r][k], W[k * FO + j], acc);
    y[(size_t)row * FO + j] = dinv[row] * acc;
}

// ---------------- single-pass sliced CSR aggregate (bf16 gather) --------------
// ONE 16-feature slice per LAUNCH (pass index p is a kernel arg): working set
// is architecturally 3.2MB < 4MB L2, drift-proof. 8 threads/node: fp = tx&1
// (feature half, uint4), q = tx>>1 (list quarter) -> 3125 blocks, R4-scale
// parallelism. Branch-free 8-deep gather batch; tail = ONE masked batch
// (clamped indices + 0/1-weight fma -> loads stay batched). Quarters reduce
// via shfl_xor(2,4) within the wave; q==0 stores (nt).
template<int F, bool RELU>
__global__ __launch_bounds__(256)
void k_agg_pass(int p, const int* __restrict__ rp, const unsigned* __restrict__ csr,
                const __hip_bfloat16* __restrict__ y, const float* __restrict__ dinv,
                const float* __restrict__ b, float* __restrict__ out) {
    const int tx = threadIdx.x;        // 0..7
    const int fp = tx & 1;             // which uint4 of the 16-feature slice row
    const int q  = tx >> 1;            // list quarter 0..3
    const int n  = blockIdx.x * 32 + threadIdx.y;
    if (n >= N) return;
    const uint4* yq = (const uint4*)y;
    const size_t sbase = (size_t)p * N * 2 + fp;   // slice base (uint4 units)

    const int rb = (n >> BUK_SHIFT) * RP_STR + (n & (BUK_NODES - 1));
    const int j0 = rp[rb];
    const int j1 = rp[rb + 1];
    const int len = j1 - j0;
    const int ql  = (len + 3) >> 2;
    int j = j0 + q * ql;
    const int je = min(j + ql, j1);

    auto unpk = [](unsigned w, float& lo, float& hi) {
        lo = __uint_as_float(w << 16);
        hi = __uint_as_float(w & 0xffff0000u);
    };

    float acc[8];
    if (q == 0) {   // self-loop owned by quarter 0
        uint4 v = yq[sbase + (size_t)n * 2];
        unpk(v.x, acc[0], acc[1]); unpk(v.y, acc[2], acc[3]);
        unpk(v.z, acc[4], acc[5]); unpk(v.w, acc[6], acc[7]);
    } else {
#pragma unroll
        for (int i = 0; i < 8; ++i) acc[i] = 0.0f;
    }
    auto accum = [&](uint4 v) {
        float l0, h0, l1, h1, l2, h2, l3, h3;
        unpk(v.x, l0, h0); unpk(v.y, l1, h1);
        unpk(v.z, l2, h2); unpk(v.w, l3, h3);
        acc[0] += l0; acc[1] += h0; acc[2] += l1; acc[3] += h1;
        acc[4] += l2; acc[5] += h2; acc[6] += l3; acc[7] += h3;
    };
    auto accum_w = [&](uint4 v, float w) {
        float l0, h0, l1, h1, l2, h2, l3, h3;
        unpk(v.x, l0, h0); unpk(v.y, l1, h1);
        unpk(v.z, l2, h2); unpk(v.w, l3, h3);
        acc[0] = fmaf(w, l0, acc[0]); acc[1] = fmaf(w, h0, acc[1]);
        acc[2] = fmaf(w, l1, acc[2]); acc[3] = fmaf(w, h1, acc[3]);
        acc[4] = fmaf(w, l2, acc[4]); acc[5] = fmaf(w, h2, acc[5]);
        acc[6] = fmaf(w, l3, acc[6]); acc[7] = fmaf(w, h3, acc[7]);
    };

    for (; j + 8 <= je; j += 8) {   // full batch: 8 x 16B gathers in flight
        int s0 = (int)__builtin_nontemporal_load(&csr[j]);
        int s1 = (int)__builtin_nontemporal_load(&csr[j + 1]);
        int s2 = (int)__builtin_nontemporal_load(&csr[j + 2]);
        int s3 = (int)__builtin_nontemporal_load(&csr[j + 3]);
        int s4 = (int)__builtin_nontemporal_load(&csr[j + 4]);
        int s5 = (int)__builtin_nontemporal_load(&csr[j + 5]);
        int s6 = (int)__builtin_nontemporal_load(&csr[j + 6]);
        int s7 = (int)__builtin_nontemporal_load(&csr[j + 7]);
        uint4 v0 = yq[sbase + (size_t)s0 * 2], v1 = yq[sbase + (size_t)s1 * 2];
        uint4 v2 = yq[sbase + (size_t)s2 * 2], v3 = yq[sbase + (size_t)s3 * 2];
        uint4 v4 = yq[sbase + (size_t)s4 * 2], v5 = yq[sbase + (size_t)s5 * 2];
        uint4 v6 = yq[sbase + (size_t)s6 * 2], v7 = yq[sbase + (size_t)s7 * 2];
        accum(v0); accum(v1); accum(v2); accum(v3);
        accum(v4); accum(v5); accum(v6); accum(v7);
    }
    if (j < je) {                   // tail: ONE masked batch, straight-line
        const int last = je - 1;
        int j0c = j,              j1c = min(j + 1, last), j2c = min(j + 2, last), j3c = min(j + 3, last);
        int j4c = min(j + 4, last), j5c = min(j + 5, last), j6c = min(j + 6, last), j7c = min(j + 7, last);
        int s0 = (int)__builtin_nontemporal_load(&csr[j0c]);
        int s1 = (int)__builtin_nontemporal_load(&csr[j1c]);
        int s2 = (int)__builtin_nontemporal_load(&csr[j2c]);
        int s3 = (int)__builtin_nontemporal_load(&csr[j3c]);
        int s4 = (int)__builtin_nontemporal_load(&csr[j4c]);
        int s5 = (int)__builtin_nontemporal_load(&csr[j5c]);
        int s6 = (int)__builtin_nontemporal_load(&csr[j6c]);
        int s7 = (int)__builtin_nontemporal_load(&csr[j7c]);
        uint4 v0 = yq[sbase + (size_t)s0 * 2], v1 = yq[sbase + (size_t)s1 * 2];
        uint4 v2 = yq[sbase + (size_t)s2 * 2], v3 = yq[sbase + (size_t)s3 * 2];
        uint4 v4 = yq[sbase + (size_t)s4 * 2], v5 = yq[sbase + (size_t)s5 * 2];
        uint4 v6 = yq[sbase + (size_t)s6 * 2], v7 = yq[sbase + (size_t)s7 * 2];
        accum(v0);
        accum_w(v1, (j + 1 < je) ? 1.f : 0.f);
        accum_w(v2, (j + 2 < je) ? 1.f : 0.f);
        accum_w(v3, (j + 3 < je) ? 1.f : 0.f);
        accum_w(v4, (j + 4 < je) ? 1.f : 0.f);
        accum_w(v5, (j + 5 < je) ? 1.f : 0.f);
        accum_w(v6, (j + 6 < je) ? 1.f : 0.f);
        accum_w(v7, (j + 7 < je) ? 1.f : 0.f);
    }

    // reduce quarters: lanes differ in tx bits 1..2 -> shfl_xor 2 then 4
#pragma unroll
    for (int i = 0; i < 8; ++i) {
        acc[i] += __shfl_xor(acc[i], 2);
        acc[i] += __shfl_xor(acc[i], 4);
    }

    if (q == 0) {
        const float di = dinv[n];
        const float* bp = b + p * 16 + 8 * fp;
        f32x4 o0, o1;
        o0.x = fmaf(di, acc[0], bp[0]);
        o0.y = fmaf(di, acc[1], bp[1]);
        o0.z = fmaf(di, acc[2], bp[2]);
        o0.w = fmaf(di, acc[3], bp[3]);
        o1.x = fmaf(di, acc[4], bp[4]);
        o1.y = fmaf(di, acc[5], bp[5]);
        o1.z = fmaf(di, acc[6], bp[6]);
        o1.w = fmaf(di, acc[7], bp[7]);
        if (RELU) {
            o0.x = fmaxf(o0.x, 0.f); o0.y = fmaxf(o0.y, 0.f);
            o0.z = fmaxf(o0.z, 0.f); o0.w = fmaxf(o0.w, 0.f);
            o1.x = fmaxf(o1.x, 0.f); o1.y = fmaxf(o1.y, 0.f);
            o1.z = fmaxf(o1.z, 0.f); o1.w = fmaxf(o1.w, 0.f);
        }
        float* op = out + (size_t)n * F + p * 16 + 8 * fp;
        __builtin_nontemporal_store(o0, (f32x4*)op);
        __builtin_nontemporal_store(o1, (f32x4*)(op + 4));
    }
}

// ---------------- layer 3 aggregate + log_softmax (2 classes) ----------------
__global__ __launch_bounds__(256)
void k_final(const int* __restrict__ rp, const unsigned* __restrict__ csr,
             const float* __restrict__ y, const float* __restrict__ dinv,
             const float* __restrict__ bias, float* __restrict__ out) {
    const int c = threadIdx.x;                       // class 0/1
    const int n = blockIdx.x * 128 + threadIdx.y;    // node
    float z = 0.0f;
    if (n < N) {
        const int rb = (n >> BUK_SHIFT) * RP_STR + (n & (BUK_NODES - 1));
        int j = rp[rb];
        const int j1 = rp[rb + 1];
        float acc = y[2 * n + c];
        for (; j + 4 <= j1; j += 4) {
            int s0 = (int)csr[j], s1 = (int)csr[j + 1], s2 = (int)csr[j + 2], s3 = (int)csr[j + 3];
            float a0 = y[2 * s0 + c], a1 = y[2 * s1 + c];
            float a2 = y[2 * s2 + c], a3 = y[2 * s3 + c];
            acc += (a0 + a1) + (a2 + a3);
        }
        for (; j < j1; ++j) acc += y[2 * (int)csr[j] + c];
        z = fmaf(dinv[n], acc, bias[c]);
    }
    float zo = __shfl_xor(z, 1);
    if (n < N) {
        float m = fmaxf(z, zo);
        float lse = m + logf(expf(z - m) + expf(zo - m));
        out[2 * n + c] = z - lse;
    }
}

extern "C" void kernel_launch(void* const* d_in, const int* in_sizes, int n_in,
                              void* d_out, int out_size, void* d_ws, size_t ws_size,
                              hipStream_t stream) {
    const float* x   = (const float*)d_in[0];
    const int*   ei  = (const int*)d_in[1];
    const float* W1  = (const float*)d_in[2];
    const float* b1  = (const float*)d_in[3];
    const float* W2  = (const float*)d_in[4];
    const float* b2  = (const float*)d_in[5];
    const float* W3  = (const float*)d_in[6];
    const float* b3  = (const float*)d_in[7];
    float* out = (float*)d_out;

    const int* src = ei;
    const int* dst = ei + E;

    // workspace layout
    char* p = (char*)d_ws;
    float*    dinv    = (float*)p;    p += (size_t)N * 4;
    int*      gcursor = (int*)p;      p += (size_t)NBUK * 4;
    int*      rp      = (int*)p;      p += (size_t)NBUK * RP_STR * 4;  // 406 KB
    unsigned* ebuf    = (unsigned*)p; p += (size_t)NBUK * CAP * 4;     // 16 MB
    char*     bufA    = p;            p += (size_t)N * 64 * 4;         // 25.6 MB
    char*     bufB    = p;            p += (size_t)N * 64 * 4;         // 25.6 MB

    __hip_bfloat16* y1 = (__hip_bfloat16*)bufA;     // [4][N][16] bf16
    float*          h1 = (float*)bufB;              // N*64*4 B
    __hip_bfloat16* y2 = (__hip_bfloat16*)bufA;     // [2][N][16] bf16 (y1 dead)
    float*          h2 = (float*)(bufA + (size_t)N * H2 * 2);  // N*32*4 B
    float*          y3 = (float*)bufB;              // N*2*4 B (h1 dead)

    // ---- edge structure build ----
    k_initcur<<<(NBUK + 255) / 256, 256, 0, stream>>>(gcursor);
    k_mslice <<<MS_WGS, MS_TPB, 0, stream>>>(src, dst, gcursor, ebuf);
    k_build  <<<NBUK, 256, 0, stream>>>(gcursor, ebuf, rp, dinv);

    const int AGG_GRID = (N + 31) / 32;   // 3125 blocks, 8 threads/node

    // ---- layer 1: 128 -> 64 ----
    k_gemm_tile_bf<FIN, H1><<<(N + 63) / 64, 256, 0, stream>>>(x, W1, dinv, y1);
    for (int pss = 0; pss < H1 / 16; ++pss)
        k_agg_pass<H1, true><<<AGG_GRID, dim3(8, 32), 0, stream>>>(pss, rp, ebuf, y1, dinv, b1, h1);

    // ---- layer 2: 64 -> 32 ----
    k_gemm_tile_bf<H1, H2><<<(N + 63) / 64, 256, 0, stream>>>(h1, W2, dinv, y2);
    for (int pss = 0; pss < H2 / 16; ++pss)
        k_agg_pass<H2, true><<<AGG_GRID, dim3(8, 32), 0, stream>>>(pss, rp, ebuf, y2, dinv, b2, h2);

    // ---- layer 3: 32 -> 2 + log_softmax ----
    k_gemm_scale<H2, COUT, 128><<<(N + 127) / 128, dim3(COUT, 128), 0, stream>>>(h2, W3, dinv, y3);
    k_final<<<(N + 127) / 128, dim3(2, 128), 0, stream>>>(rp, ebuf, y3, dinv, b3, out);
}

// Round 8
// 364.977 us; speedup vs baseline: 1.4252x; 1.2904x over previous
//
#include <hip/hip_runtime.h>
#include <hip/hip_bf16.h>
#include <math.h>

// Problem constants (from reference)
constexpr int N = 100000;    // nodes
constexpr int E = 3200000;   // edges
constexpr int FIN = 128, H1 = 64, H2 = 32, COUT = 2;

// Bucketing: 64 dst-nodes per bucket, fixed-capacity slices
constexpr int BUK_SHIFT = 6;
constexpr int BUK_NODES = 64;                          // 1 << BUK_SHIFT
constexpr int NBUK = (N + BUK_NODES - 1) / BUK_NODES;  // 1563
constexpr int CAP = 2560;             // slice capacity; mean fill 2048, sigma~45
// Keys LD-MAJOR (key = ld*7 + seg): node lists contiguous, R0/R4 proven.
// Aggregate: R4's flat uint4-gather walk = 89.3us at the random-gather byte
// ceiling (~3.6 TB/s on the L2-miss path; falsified: address-rate R4,
// src-phasing R1-R3, feature-slicing R5-R7 — all worse or equal).
// R8 target: the GEMMs. R7 counters exposed k_gemm_tile_bf at 53.9us
// (VALU 25%, occ 29%) vs an 11us memory floor — stalled on per-iter global
// W loads + LDS BW (1.5 B/fma). Fix: MFMA (0.25 B/mac operand traffic) with
// 3-product fp32-split (xh*wh + xh*wl + xl*wh) to keep fp32-level accuracy.
constexpr int SEG_SHIFT = 14;
constexpr int NSEG = 7;
constexpr int KEYS = BUK_NODES * NSEG;                 // 448 (ld-major!)
constexpr int RP_STR = BUK_NODES + 1;                  // 65 rowptr slots per bucket

constexpr int MS_TPB = 1024;
constexpr int MS_EPT = 24;                             // edges per thread
constexpr int CHUNK = MS_TPB * MS_EPT;                 // 24576
constexpr int MS_WGS = (E + CHUNK - 1) / CHUNK;        // 131

typedef float f32x4 __attribute__((ext_vector_type(4)));   // native clang vec
typedef short bf16x8 __attribute__((ext_vector_type(8)));  // MFMA A/B frag (4 VGPR)
typedef short s16x4 __attribute__((ext_vector_type(4)));

// ---------------- init: gcursor[b] = b*CAP ----------------
__global__ void k_initcur(int* __restrict__ gcursor) {
    int i = blockIdx.x * blockDim.x + threadIdx.x;
    if (i < NBUK) gcursor[i] = i * CAP;
}

// ---------------- multisplit into fixed-capacity bucket slices ----------------
// packed entry: src (17 bits) | local_node (6 bits) << 17
__global__ __launch_bounds__(MS_TPB)
void k_mslice(const int* __restrict__ src, const int* __restrict__ dst,
              int* __restrict__ gcursor, unsigned* __restrict__ ebuf) {
    __shared__ int cnt[NBUK];
    __shared__ int base[NBUK];
    const int t = threadIdx.x;
    for (int i = t; i < NBUK; i += MS_TPB) cnt[i] = 0;
    __syncthreads();
    const int e0 = blockIdx.x * CHUNK;

    int rb[MS_EPT];
    unsigned rv[MS_EPT];
#pragma unroll
    for (int j = 0; j < MS_EPT; ++j) {
        int e = e0 + j * MS_TPB + t;
        if (e < E) {
            int d = dst[e];
            int b = d >> BUK_SHIFT;
            rb[j] = b;
            rv[j] = (unsigned)src[e] | ((unsigned)(d & (BUK_NODES - 1)) << 17);
            atomicAdd(&cnt[b], 1);
        } else {
            rb[j] = -1; rv[j] = 0;
        }
    }
    __syncthreads();
    for (int i = t; i < NBUK; i += MS_TPB) {
        int c = cnt[i];
        base[i] = c ? atomicAdd(&gcursor[i], c) : 0;
    }
    __syncthreads();
    for (int i = t; i < NBUK; i += MS_TPB) cnt[i] = 0;
    __syncthreads();
#pragma unroll
    for (int j = 0; j < MS_EPT; ++j) {
        int b = rb[j];
        if (b >= 0) {
            int r = atomicAdd(&cnt[b], 1);
            int p = base[b] + r;
            if (p < (b + 1) * CAP) ebuf[p] = rv[j];   // overflow guard (statistically impossible)
        }
    }
}

// ---------------- per-bucket build: counting-sort by (local_dst, seg) ----------------
// ld-major key => each node's list is contiguous AND seg-sorted within.
// Emits rp[b*65 + ld] = node list start, rp[b*65+64] = slice end; dinv.
__global__ __launch_bounds__(256)
void k_build(const int* __restrict__ gcursor, unsigned* __restrict__ ebuf,
             int* __restrict__ rp, float* __restrict__ dinv) {
    __shared__ unsigned ent[CAP];
    __shared__ int cnt[512];
    __shared__ int sa[512];
    __shared__ int sb[512];
    __shared__ int cur[512];
    const int b = blockIdx.x;
    const int t = threadIdx.x;
    int fill = gcursor[b] - b * CAP;
    if (fill > CAP) fill = CAP;
    const int gbase = b * CAP;

    cnt[t] = 0; cnt[t + 256] = 0;
    __syncthreads();
    for (int j = t; j < fill; j += 256) {
        unsigned v = ebuf[gbase + j];
        ent[j] = v;
        int key = (int)(v >> 17) * NSEG + (int)((v & 0x1FFFFu) >> SEG_SHIFT);
        atomicAdd(&cnt[key], 1);
    }
    __syncthreads();
    sa[t] = cnt[t]; sa[t + 256] = cnt[t + 256];
    __syncthreads();
    int* pin = sa; int* pout = sb;
    for (int off = 1; off < 512; off <<= 1) {
        pout[t]       = pin[t]       + ((t >= off)       ? pin[t - off]       : 0);
        pout[t + 256] = pin[t + 256] + ((t + 256 >= off) ? pin[t + 256 - off] : 0);
        __syncthreads();
        int* tmp = pin; pin = pout; pout = tmp;
    }
    {
        int ex0 = pin[t] - cnt[t];
        int ex1 = pin[t + 256] - cnt[t + 256];
        cur[t] = gbase + ex0;
        cur[t + 256] = gbase + ex1;
        // node list start = start of its first (seg=0) key
        if (t < KEYS && (t % NSEG) == 0)
            rp[b * RP_STR + t / NSEG] = gbase + ex0;
        int k2 = t + 256;
        if (k2 < KEYS && (k2 % NSEG) == 0)
            rp[b * RP_STR + k2 / NSEG] = gbase + ex1;
        if (t == 0) rp[b * RP_STR + BUK_NODES] = gbase + fill;   // sentinel
    }
    if (t < BUK_NODES) {
        int deg = 0;
#pragma unroll
        for (int s = 0; s < NSEG; ++s) deg += cnt[t * NSEG + s];
        int node = (b << BUK_SHIFT) + t;
        if (node < N) dinv[node] = rsqrtf((float)deg + 1.0f);  // self-loop included
    }
    __syncthreads();
    for (int j = t; j < fill; j += 256) {
        unsigned v = ent[j];
        int key = (int)(v >> 17) * NSEG + (int)((v & 0x1FFFFu) >> SEG_SHIFT);
        int p = atomicAdd(&cur[key], 1);
        ebuf[p] = v & 0x1FFFFu;   // sorted, plain src
    }
}

// ---------------- MFMA GEMM + dinv scale, bf16 output (fp32-split accuracy) ---
// Block: 64 rows x FO cols, 256 threads = 4 waves; wave w -> rows [16w,16w+16).
// K phased in KH=64-wide halves (LDS 37KB -> 4 blocks/CU). x and W are split
// into bf16 hi+lo; D = xh*wh + xh*wl + xl*wh (residual ~2^-18, fp32-level).
// Fragments (mfma_f32_16x16x32_bf16): A row=lane&15, k=8*(lane>>4)+i;
// B col=lane&15 (same k map); C/D col=lane&15, row=4*(lane>>4)+reg (m89).
template<int FI, int FO>
__global__ __launch_bounds__(256)
void k_gemm_mfma(const float* __restrict__ h, const float* __restrict__ Wg,
                 const float* __restrict__ dinv, __hip_bfloat16* __restrict__ y) {
    constexpr int KH  = (FI > 64) ? 64 : FI;   // k-phase width
    constexpr int NPH = FI / KH;
    constexpr int KP  = KH + 8;                // pad: stride 144B -> 2-way banks (free)
    constexpr int NCT = FO / 16;               // 16-col tiles per wave

    __shared__ short xh[64 * KP];
    __shared__ short xl[64 * KP];
    __shared__ short wh[FO * KP];
    __shared__ short wl[FO * KP];

    const int tid = threadIdx.x;
    const int w   = tid >> 6;
    const int l   = tid & 63;
    const int lm  = l & 15;       // M-idx (A) / N-idx (B)
    const int lg  = l >> 4;       // k-octet
    const int row0 = blockIdx.x * 64;

    auto cvt_hi = [](float f) -> short {
        __hip_bfloat16 b = __float2bfloat16(f);
        return *reinterpret_cast<short*>(&b);
    };
    auto bf2f = [](short s) -> float {
        return __uint_as_float(((unsigned)(unsigned short)s) << 16);
    };

    f32x4 acc[NCT];
#pragma unroll
    for (int ct = 0; ct < NCT; ++ct) acc[ct] = f32x4{0.f, 0.f, 0.f, 0.f};

    for (int ph = 0; ph < NPH; ++ph) {
        if (ph) __syncthreads();   // all waves done with previous phase's LDS
        // stage x[row0..row0+64)[ph*KH .. +KH) as hi/lo bf16
        for (int idx = tid; idx < 64 * KH / 4; idx += 256) {
            int r  = idx / (KH / 4);
            int k4 = idx % (KH / 4);
            int row = row0 + r;
            float4 v = make_float4(0.f, 0.f, 0.f, 0.f);
            if (row < N) v = *(const float4*)(h + (size_t)row * FI + ph * KH + 4 * k4);
            float vv[4] = {v.x, v.y, v.z, v.w};
            s16x4 ph4, pl4;
#pragma unroll
            for (int i = 0; i < 4; ++i) {
                short hi = cvt_hi(vv[i]);
                ph4[i] = hi;
                pl4[i] = cvt_hi(vv[i] - bf2f(hi));
            }
            *(s16x4*)&xh[r * KP + 4 * k4] = ph4;
            *(s16x4*)&xl[r * KP + 4 * k4] = pl4;
        }
        // stage W rows [ph*KH .. +KH), transposed: wh[c][k]
        for (int idx = tid; idx < KH * FO; idx += 256) {
            int k = idx / FO;
            int c = idx % FO;
            float wv = Wg[(size_t)(ph * KH + k) * FO + c];
            short hi = cvt_hi(wv);
            wh[c * KP + k] = hi;
            wl[c * KP + k] = cvt_hi(wv - bf2f(hi));
        }
        __syncthreads();

#pragma unroll
        for (int k0 = 0; k0 < KH; k0 += 32) {
            const int ka = (16 * w + lm) * KP + k0 + 8 * lg;
            bf16x8 ah = *(const bf16x8*)&xh[ka];
            bf16x8 al = *(const bf16x8*)&xl[ka];
#pragma unroll
            for (int ct = 0; ct < NCT; ++ct) {
                const int kb = (16 * ct + lm) * KP + k0 + 8 * lg;
                bf16x8 bh = *(const bf16x8*)&wh[kb];
                bf16x8 bl = *(const bf16x8*)&wl[kb];
                acc[ct] = __builtin_amdgcn_mfma_f32_16x16x32_bf16(ah, bh, acc[ct], 0, 0, 0);
                acc[ct] = __builtin_amdgcn_mfma_f32_16x16x32_bf16(ah, bl, acc[ct], 0, 0, 0);
                acc[ct] = __builtin_amdgcn_mfma_f32_16x16x32_bf16(al, bh, acc[ct], 0, 0, 0);
            }
        }
    }

    // epilogue: D row = 16w + 4*lg + i, col = 16*ct + lm
    float di[4];
#pragma unroll
    for (int i = 0; i < 4; ++i) {
        int row = row0 + 16 * w + 4 * lg + i;
        di[i] = (row < N) ? dinv[row] : 0.f;
    }
#pragma unroll
    for (int ct = 0; ct < NCT; ++ct) {
#pragma unroll
        for (int i = 0; i < 4; ++i) {
            int row = row0 + 16 * w + 4 * lg + i;
            if (row < N)
                y[(size_t)row * FO + 16 * ct + lm] = __float2bfloat16(di[i] * acc[ct][i]);
        }
    }
}

// ---------------- fused GEMM + dinv scale, fp32 output (layer 3, tiny) ----------------
template<int FI, int FO, int ROWS>
__global__ __launch_bounds__(FO * ROWS)
void k_gemm_scale(const float* __restrict__ h, const float* __restrict__ W,
                  const float* __restrict__ dinv, float* __restrict__ y) {
    __shared__ float xs[ROWS][FI];
    const int j = threadIdx.x;
    const int r = threadIdx.y;
    const int row0 = blockIdx.x * ROWS;
    const int tid = r * FO + j;
    constexpr int NT = FO * ROWS;
    for (int t = tid; t < ROWS * FI; t += NT) {
        int rr = t / FI, kk = t % FI;
        int row = row0 + rr;
        xs[rr][kk] = (row < N) ? h[(size_t)row * FI + kk] : 0.0f;
    }
    __syncthreads();
    const int row = row0 + r;
    if (row >= N) return;
    float acc = 0.0f;
#pragma unroll
    for (int k = 0; k < FI; ++k)
        acc = fmaf(xs[r][k], W[k * FO + j], acc);
    y[(size_t)row * FO + j] = dinv[row] * acc;
}

// ---------------- CSR aggregate, 16B vectorized gather + fused epilogue -------
// R4's proven flat per-node walk (89.3us, random-gather byte ceiling).
template<int F, bool RELU>
__global__ __launch_bounds__(256)
void k_agg_v(const int* __restrict__ rp, const unsigned* __restrict__ csr,
             const __hip_bfloat16* __restrict__ y, const float* __restrict__ dinv,
             const float* __restrict__ b, float* __restrict__ out) {
    constexpr int LPN = F / 8;         // lanes per node (uint4 slots per row)
    constexpr int NPB = 256 / LPN;     // nodes per block
    const int fp = threadIdx.x;        // uint4 slot index within row
    const int n = blockIdx.x * NPB + threadIdx.y;
    if (n >= N) return;
    const uint4* yq = (const uint4*)y;          // row stride = LPN uint4s

    float acc[8];
    auto unpk = [](unsigned w, float& lo, float& hi) {
        lo = __uint_as_float(w << 16);
        hi = __uint_as_float(w & 0xffff0000u);
    };
    auto accum = [&](uint4 v) {
        float l0, h0, l1, h1, l2, h2, l3, h3;
        unpk(v.x, l0, h0); unpk(v.y, l1, h1);
        unpk(v.z, l2, h2); unpk(v.w, l3, h3);
        acc[0] += l0; acc[1] += h0; acc[2] += l1; acc[3] += h1;
        acc[4] += l2; acc[5] += h2; acc[6] += l3; acc[7] += h3;
    };

    // self-loop init
    {
        uint4 v = yq[(size_t)n * LPN + fp];
        float l0, h0, l1, h1, l2, h2, l3, h3;
        unpk(v.x, l0, h0); unpk(v.y, l1, h1);
        unpk(v.z, l2, h2); unpk(v.w, l3, h3);
        acc[0] = l0; acc[1] = h0; acc[2] = l1; acc[3] = h1;
        acc[4] = l2; acc[5] = h2; acc[6] = l3; acc[7] = h3;
    }

    const int rb = (n >> BUK_SHIFT) * RP_STR + (n & (BUK_NODES - 1));
    int j = rp[rb];
    const int j1 = rp[rb + 1];
    for (; j + 8 <= j1; j += 8) {   // 8 x 16B gathers in flight per lane
        int s0 = (int)csr[j],     s1 = (int)csr[j + 1], s2 = (int)csr[j + 2], s3 = (int)csr[j + 3];
        int s4 = (int)csr[j + 4], s5 = (int)csr[j + 5], s6 = (int)csr[j + 6], s7 = (int)csr[j + 7];
        uint4 v0 = yq[(size_t)s0 * LPN + fp], v1 = yq[(size_t)s1 * LPN + fp];
        uint4 v2 = yq[(size_t)s2 * LPN + fp], v3 = yq[(size_t)s3 * LPN + fp];
        uint4 v4 = yq[(size_t)s4 * LPN + fp], v5 = yq[(size_t)s5 * LPN + fp];
        uint4 v6 = yq[(size_t)s6 * LPN + fp], v7 = yq[(size_t)s7 * LPN + fp];
        accum(v0); accum(v1); accum(v2); accum(v3);
        accum(v4); accum(v5); accum(v6); accum(v7);
    }
    for (; j < j1; ++j) {
        uint4 v = yq[(size_t)(int)csr[j] * LPN + fp];
        accum(v);
    }

    const float di = dinv[n];
    float4 o0, o1;
    o0.x = fmaf(di, acc[0], b[8 * fp + 0]);
    o0.y = fmaf(di, acc[1], b[8 * fp + 1]);
    o0.z = fmaf(di, acc[2], b[8 * fp + 2]);
    o0.w = fmaf(di, acc[3], b[8 * fp + 3]);
    o1.x = fmaf(di, acc[4], b[8 * fp + 4]);
    o1.y = fmaf(di, acc[5], b[8 * fp + 5]);
    o1.z = fmaf(di, acc[6], b[8 * fp + 6]);
    o1.w = fmaf(di, acc[7], b[8 * fp + 7]);
    if (RELU) {
        o0.x = fmaxf(o0.x, 0.f); o0.y = fmaxf(o0.y, 0.f);
        o0.z = fmaxf(o0.z, 0.f); o0.w = fmaxf(o0.w, 0.f);
        o1.x = fmaxf(o1.x, 0.f); o1.y = fmaxf(o1.y, 0.f);
        o1.z = fmaxf(o1.z, 0.f); o1.w = fmaxf(o1.w, 0.f);
    }
    float* op = out + (size_t)n * F + 8 * fp;
    *(float4*)op = o0;
    *(float4*)(op + 4) = o1;
}

// ---------------- layer 3 aggregate + log_softmax (2 classes) ----------------
__global__ __launch_bounds__(256)
void k_final(const int* __restrict__ rp, const unsigned* __restrict__ csr,
             const float* __restrict__ y, const float* __restrict__ dinv,
             const float* __restrict__ bias, float* __restrict__ out) {
    const int c = threadIdx.x;                       // class 0/1
    const int n = blockIdx.x * 128 + threadIdx.y;    // node
    float z = 0.0f;
    if (n < N) {
        const int rb = (n >> BUK_SHIFT) * RP_STR + (n & (BUK_NODES - 1));
        int j = rp[rb];
        const int j1 = rp[rb + 1];
        float acc = y[2 * n + c];
        for (; j + 4 <= j1; j += 4) {
            int s0 = (int)csr[j], s1 = (int)csr[j + 1], s2 = (int)csr[j + 2], s3 = (int)csr[j + 3];
            float a0 = y[2 * s0 + c], a1 = y[2 * s1 + c];
            float a2 = y[2 * s2 + c], a3 = y[2 * s3 + c];
            acc += (a0 + a1) + (a2 + a3);
        }
        for (; j < j1; ++j) acc += y[2 * (int)csr[j] + c];
        z = fmaf(dinv[n], acc, bias[c]);
    }
    float zo = __shfl_xor(z, 1);
    if (n < N) {
        float m = fmaxf(z, zo);
        float lse = m + logf(expf(z - m) + expf(zo - m));
        out[2 * n + c] = z - lse;
    }
}

extern "C" void kernel_launch(void* const* d_in, const int* in_sizes, int n_in,
                              void* d_out, int out_size, void* d_ws, size_t ws_size,
                              hipStream_t stream) {
    const float* x   = (const float*)d_in[0];
    const int*   ei  = (const int*)d_in[1];
    const float* W1  = (const float*)d_in[2];
    const float* b1  = (const float*)d_in[3];
    const float* W2  = (const float*)d_in[4];
    const float* b2  = (const float*)d_in[5];
    const float* W3  = (const float*)d_in[6];
    const float* b3  = (const float*)d_in[7];
    float* out = (float*)d_out;

    const int* src = ei;
    const int* dst = ei + E;

    // workspace layout
    char* p = (char*)d_ws;
    float*    dinv    = (float*)p;    p += (size_t)N * 4;
    int*      gcursor = (int*)p;      p += (size_t)NBUK * 4;
    int*      rp      = (int*)p;      p += (size_t)NBUK * RP_STR * 4;  // 406 KB
    unsigned* ebuf    = (unsigned*)p; p += (size_t)NBUK * CAP * 4;     // 16 MB
    char*     bufA    = p;            p += (size_t)N * 64 * 4;         // 25.6 MB
    char*     bufB    = p;            p += (size_t)N * 64 * 4;         // 25.6 MB

    __hip_bfloat16* y1 = (__hip_bfloat16*)bufA;     // N*64*2 B
    float*          h1 = (float*)bufB;              // N*64*4 B
    __hip_bfloat16* y2 = (__hip_bfloat16*)bufA;     // N*32*2 B (y1 dead)
    float*          h2 = (float*)(bufA + (size_t)N * H2 * 2);  // N*32*4 B
    float*          y3 = (float*)bufB;              // N*2*4 B (h1 dead)

    // ---- edge structure build ----
    k_initcur<<<(NBUK + 255) / 256, 256, 0, stream>>>(gcursor);
    k_mslice <<<MS_WGS, MS_TPB, 0, stream>>>(src, dst, gcursor, ebuf);
    k_build  <<<NBUK, 256, 0, stream>>>(gcursor, ebuf, rp, dinv);

    // ---- layer 1: 128 -> 64 ----
    k_gemm_mfma<FIN, H1><<<(N + 63) / 64, 256, 0, stream>>>(x, W1, dinv, y1);
    k_agg_v<H1, true><<<(N + 31) / 32, dim3(8, 32), 0, stream>>>(rp, ebuf, y1, dinv, b1, h1);

    // ---- layer 2: 64 -> 32 ----
    k_gemm_mfma<H1, H2><<<(N + 63) / 64, 256, 0, stream>>>(h1, W2, dinv, y2);
    k_agg_v<H2, true><<<(N + 63) / 64, dim3(4, 64), 0, stream>>>(rp, ebuf, y2, dinv, b2, h2);

    // ---- layer 3: 32 -> 2 + log_softmax ----
    k_gemm_scale<H2, COUT, 128><<<(N + 127) / 128, dim3(COUT, 128), 0, stream>>>(h2, W3, dinv, y3);
    k_final<<<(N + 127) / 128, dim3(2, 128), 0, stream>>>(rp, ebuf, y3, dinv, b3, out);
}